// Round 4
// baseline (356.905 us; speedup 1.0000x reference)
//
#include <hip/hip_runtime.h>
#include <stdint.h>

// Problem constants (B=1)
#define L_SEQ 2048
#define DMODEL 1024
#define DI_DIM 2048
#define NSSM 16
#define NPROJ 2080        // DI + 2N
#define NCHUNK 64
#define LCHUNK 32         // NCHUNK*LCHUNK == L_SEQ

typedef __attribute__((ext_vector_type(8))) short bf16x8;
typedef __attribute__((ext_vector_type(4))) float f32x4;

__device__ __forceinline__ float bf2f(unsigned short u) {
  union { uint32_t u; float f; } v; v.u = (uint32_t)u << 16; return v.f;
}
__device__ __forceinline__ unsigned short f2bf(float f) {
  union { float f; uint32_t u; } v; v.f = f;
  uint32_t u = v.u;
  return (unsigned short)((u + 0x7fffu + ((u >> 16) & 1u)) >> 16);
}
__device__ __forceinline__ void async16(const void* g, void* l) {
  __builtin_amdgcn_global_load_lds(
      (__attribute__((address_space(1))) void*)(g),
      (__attribute__((address_space(3))) void*)(l), 16, 0, 0);
}

// ---------------- fp32 -> bf16 convert (vec4) ----------------
__global__ void k_f32_to_bf16(const float* __restrict__ in,
                              unsigned short* __restrict__ out, int n4) {
  int i = blockIdx.x * blockDim.x + threadIdx.x;
  if (i < n4) {
    const float4 v = ((const float4*)in)[i];
    ushort4 o;
    o.x = f2bf(v.x); o.y = f2bf(v.y); o.z = f2bf(v.z); o.w = f2bf(v.w);
    ((ushort4*)out)[i] = o;
  }
}

// ---------------- bf16 N-T GEMM: C[M,N] = A[M,K] * B[N,K]^T + bias(f32) ----------------
// m97-style: 128x128 tile, BK=32, 4 waves, each wave 4x4 of 16x16x32 MFMA,
// global_load_lds width-16 staging into unpadded [128][32] LDS tiles.
// OutT = float (f32 store) or unsigned short (bf16 store).
template <typename OutT>
__global__ __launch_bounds__(256) void k_gemm_bt(
    const unsigned short* __restrict__ A, const unsigned short* __restrict__ B,
    const float* __restrict__ bias, OutT* __restrict__ C,
    int M, int N, int K) {
  __shared__ unsigned short As[128 * 32];
  __shared__ unsigned short Bs[128 * 32];
  const int tid = threadIdx.x;
  const int wave = tid >> 6;
  const int lane = tid & 63;
  const int m0 = blockIdx.y * 128;
  const int n0 = blockIdx.x * 128;

  // staging: each wave issues 2 A + 2 B global_load_lds (16B/lane, 16 rows/instr)
  const int srow = wave * 32 + (lane >> 2);
  const int scol = (lane & 3) * 8;
  int ar0 = m0 + srow;      if (ar0 > M - 1) ar0 = M - 1;
  int ar1 = m0 + srow + 16; if (ar1 > M - 1) ar1 = M - 1;
  int br0 = n0 + srow;      if (br0 > N - 1) br0 = N - 1;
  int br1 = n0 + srow + 16; if (br1 > N - 1) br1 = N - 1;
  const unsigned short* ap0 = A + (size_t)ar0 * K + scol;
  const unsigned short* ap1 = A + (size_t)ar1 * K + scol;
  const unsigned short* bp0 = B + (size_t)br0 * K + scol;
  const unsigned short* bp1 = B + (size_t)br1 * K + scol;
  unsigned short* as0 = &As[(wave * 32) * 32];
  unsigned short* as1 = &As[(wave * 32 + 16) * 32];
  unsigned short* bs0 = &Bs[(wave * 32) * 32];
  unsigned short* bs1 = &Bs[(wave * 32 + 16) * 32];

  const int wm = wave & 1;
  const int wn = wave >> 1;
  const int fr = lane & 15;
  const int fk = (lane >> 4) * 8;

  f32x4 acc[4][4];
#pragma unroll
  for (int i = 0; i < 4; i++)
#pragma unroll
    for (int j = 0; j < 4; j++) acc[i][j] = (f32x4){0.f, 0.f, 0.f, 0.f};

  for (int kt = 0; kt < K; kt += 32) {
    async16(ap0 + kt, as0);
    async16(ap1 + kt, as1);
    async16(bp0 + kt, bs0);
    async16(bp1 + kt, bs1);
    __syncthreads();
    bf16x8 af[4], bfv[4];
#pragma unroll
    for (int i = 0; i < 4; i++)
      af[i] = *(const bf16x8*)&As[(wm * 64 + i * 16 + fr) * 32 + fk];
#pragma unroll
    for (int j = 0; j < 4; j++)
      bfv[j] = *(const bf16x8*)&Bs[(wn * 64 + j * 16 + fr) * 32 + fk];
#pragma unroll
    for (int i = 0; i < 4; i++)
#pragma unroll
      for (int j = 0; j < 4; j++)
        acc[i][j] = __builtin_amdgcn_mfma_f32_16x16x32_bf16(af[i], bfv[j], acc[i][j], 0, 0, 0);
    __syncthreads();
  }

  // epilogue: C/D layout col=lane&15, row=(lane>>4)*4+reg (verified mapping)
#pragma unroll
  for (int j = 0; j < 4; j++) {
    int col = n0 + wn * 64 + j * 16 + fr;
    if (col < N) {
      float bv = bias[col];
#pragma unroll
      for (int i = 0; i < 4; i++) {
        int rbase = m0 + wm * 64 + i * 16 + (lane >> 4) * 4;
#pragma unroll
        for (int r = 0; r < 4; r++) {
          float v = acc[i][j][r] + bv;
          if constexpr (sizeof(OutT) == 2)
            C[(size_t)(rbase + r) * N + col] = (OutT)f2bf(v);
          else
            C[(size_t)(rbase + r) * N + col] = (OutT)v;
        }
      }
    }
  }
}

// ---------------- depthwise causal conv (K=4) + bias + SiLU ----------------
// xr is bf16 [L, 2*DI]; columns 0..DI-1 are xi. Output bf16 [L, DI].
__global__ void k_conv_silu(const unsigned short* __restrict__ xr,
                            const float* __restrict__ Wc,
                            const float* __restrict__ bc,
                            unsigned short* __restrict__ xcb) {
  int idx = blockIdx.x * blockDim.x + threadIdx.x;
  if (idx >= L_SEQ * DI_DIM) return;
  int t = idx >> 11;
  int d = idx & (DI_DIM - 1);
  float acc = bc[d];
  const float* wd = Wc + d * 4;
  if (t >= 3) acc += bf2f(xr[(size_t)(t - 3) * (2 * DI_DIM) + d]) * wd[0];
  if (t >= 2) acc += bf2f(xr[(size_t)(t - 2) * (2 * DI_DIM) + d]) * wd[1];
  if (t >= 1) acc += bf2f(xr[(size_t)(t - 1) * (2 * DI_DIM) + d]) * wd[2];
  acc += bf2f(xr[(size_t)t * (2 * DI_DIM) + d]) * wd[3];
  float s = acc / (1.f + __expf(-acc));
  xcb[idx] = f2bf(s);
}

__device__ __forceinline__ float softplusf(float p) {
  return (p > 20.f) ? p : log1pf(__expf(p));
}

// ---------------- scan phase A: per-chunk local scan ----------------
__global__ __launch_bounds__(256) void k_scan_a(
    const float* __restrict__ proj, const unsigned short* __restrict__ xcb,
    const float* __restrict__ A_log,
    float* __restrict__ Sdelta, float* __restrict__ hstate) {
  __shared__ float Bsh[LCHUNK * NSSM];
  const int d = blockIdx.x * 256 + threadIdx.x;
  const int c = blockIdx.y;
  const int t0 = c * LCHUNK;
  for (int i = threadIdx.x; i < LCHUNK * NSSM; i += 256) {
    int t = i >> 4, n = i & 15;
    Bsh[i] = proj[(size_t)(t0 + t) * NPROJ + DI_DIM + n];
  }
  __syncthreads();
  float Ar[NSSM], h[NSSM];
#pragma unroll
  for (int n = 0; n < NSSM; n++) {
    Ar[n] = -__expf(A_log[d * NSSM + n]);
    h[n] = 0.f;
  }
  float sd = 0.f;
  for (int t = 0; t < LCHUNK; t++) {
    int tt = t0 + t;
    float delta = softplusf(proj[(size_t)tt * NPROJ + d]);
    float xi = bf2f(xcb[(size_t)tt * DI_DIM + d]);
    float dx = delta * xi;
    sd += delta;
#pragma unroll
    for (int n = 0; n < NSSM; n++)
      h[n] = __expf(delta * Ar[n]) * h[n] + dx * Bsh[t * NSSM + n];
  }
  Sdelta[(size_t)c * DI_DIM + d] = sd;
#pragma unroll
  for (int n = 0; n < NSSM; n++)
    hstate[((size_t)c * DI_DIM + d) * NSSM + n] = h[n];
}

// ---------------- scan phase B: combine across chunks (in-place: hstate -> h0) ----------------
__global__ void k_scan_b(const float* __restrict__ A_log,
                         const float* __restrict__ Sdelta,
                         float* __restrict__ hstate) {
  int tid = blockIdx.x * 256 + threadIdx.x;  // 0..32767, = d*16+n
  int d = tid >> 4;
  float A = -__expf(A_log[tid]);
  float carry = 0.f;
  for (int c = 0; c < NCHUNK; c++) {
    size_t idx = (size_t)c * DI_DIM * NSSM + tid;
    float v = hstate[idx];
    hstate[idx] = carry;  // becomes h0 for chunk c
    carry = __expf(A * Sdelta[(size_t)c * DI_DIM + d]) * carry + v;
  }
}

// ---------------- scan phase C: replay with h0, produce y*silu(res) ----------------
__global__ __launch_bounds__(256) void k_scan_c(
    const float* __restrict__ proj, const unsigned short* __restrict__ xcb,
    const float* __restrict__ A_log, const float* __restrict__ h0,
    const float* __restrict__ Dvec, const unsigned short* __restrict__ xr,
    unsigned short* __restrict__ ybf) {
  __shared__ float Bsh[LCHUNK * NSSM];
  __shared__ float Csh[LCHUNK * NSSM];
  const int d = blockIdx.x * 256 + threadIdx.x;
  const int c = blockIdx.y;
  const int t0 = c * LCHUNK;
  for (int i = threadIdx.x; i < LCHUNK * NSSM; i += 256) {
    int t = i >> 4, n = i & 15;
    Bsh[i] = proj[(size_t)(t0 + t) * NPROJ + DI_DIM + n];
    Csh[i] = proj[(size_t)(t0 + t) * NPROJ + DI_DIM + NSSM + n];
  }
  __syncthreads();
  float Ar[NSSM], h[NSSM];
#pragma unroll
  for (int n = 0; n < NSSM; n++) {
    Ar[n] = -__expf(A_log[d * NSSM + n]);
    h[n] = h0[((size_t)c * DI_DIM + d) * NSSM + n];
  }
  float Dd = Dvec[d];
  for (int t = 0; t < LCHUNK; t++) {
    int tt = t0 + t;
    float delta = softplusf(proj[(size_t)tt * NPROJ + d]);
    float xi = bf2f(xcb[(size_t)tt * DI_DIM + d]);
    float dx = delta * xi;
    float y = 0.f;
#pragma unroll
    for (int n = 0; n < NSSM; n++) {
      h[n] = __expf(delta * Ar[n]) * h[n] + dx * Bsh[t * NSSM + n];
      y += h[n] * Csh[t * NSSM + n];
    }
    y += xi * Dd;
    float res = bf2f(xr[(size_t)tt * (2 * DI_DIM) + DI_DIM + d]);
    y *= res / (1.f + __expf(-res));
    ybf[(size_t)tt * DI_DIM + d] = f2bf(y);
  }
}

extern "C" void kernel_launch(void* const* d_in, const int* in_sizes, int n_in,
                              void* d_out, int out_size, void* d_ws, size_t ws_size,
                              hipStream_t stream) {
  // inputs: float32 per reference; output: float32 (reference output dtype)
  const float* x      = (const float*)d_in[0];
  const float* W_in   = (const float*)d_in[1];
  const float* b_in   = (const float*)d_in[2];
  const float* W_conv = (const float*)d_in[3];
  const float* b_conv = (const float*)d_in[4];
  const float* W_x    = (const float*)d_in[5];
  const float* b_x    = (const float*)d_in[6];
  const float* W_out  = (const float*)d_in[7];
  const float* b_out  = (const float*)d_in[8];
  const float* A_log  = (const float*)d_in[9];
  const float* Dv     = (const float*)d_in[10];
  float* out = (float*)d_out;

  char* ws = (char*)d_ws;
  size_t off = 0;
  auto alloc = [&](size_t bytes) { void* p = ws + off; off += (bytes + 255) & ~(size_t)255; return p; };
  // shared weight buffer: W_in_bf (8.39MB) -> W_x_bf (8.52MB) -> W_out_bf (4.2MB), sequential reuse
  unsigned short* w_bf   = (unsigned short*)alloc((size_t)NPROJ * DI_DIM * 2);       // 8.52 MB (max of the three)
  unsigned short* x_bf   = (unsigned short*)alloc((size_t)L_SEQ * DMODEL * 2);       // 4.2 MB
  unsigned short* xr_bf  = (unsigned short*)alloc((size_t)L_SEQ * 2 * DI_DIM * 2);   // 16.8 MB
  unsigned short* xcb    = (unsigned short*)alloc((size_t)L_SEQ * DI_DIM * 2);       // 8.4 MB
  float* proj            = (float*)alloc((size_t)L_SEQ * NPROJ * 4);                 // 17.0 MB
  float* Sdelta          = (float*)alloc((size_t)NCHUNK * DI_DIM * 4);               // 0.5 MB
  float* hstate          = (float*)alloc((size_t)NCHUNK * DI_DIM * NSSM * 4);        // 8.4 MB
  unsigned short* ybf    = (unsigned short*)alloc((size_t)L_SEQ * DI_DIM * 2);       // 8.4 MB
  if (off > ws_size) return;  // ws too small -> clean zero-output failure (absmax 2.17e-2 signature)

  // convert x and W_in to bf16
  {
    int n4 = (L_SEQ * DMODEL) / 4;
    k_f32_to_bf16<<<(n4 + 255) / 256, 256, 0, stream>>>(x, x_bf, n4);
    n4 = (4096 * DMODEL) / 4;
    k_f32_to_bf16<<<(n4 + 255) / 256, 256, 0, stream>>>(W_in, w_bf, n4);
  }
  // GEMM1: xr = x @ W_in^T + b_in   (2048 x 4096, K=1024), bf16 out
  {
    dim3 g(4096 / 128, L_SEQ / 128);
    k_gemm_bt<unsigned short><<<g, 256, 0, stream>>>(x_bf, w_bf, b_in, xr_bf, L_SEQ, 4096, DMODEL);
  }
  // depthwise conv + SiLU
  k_conv_silu<<<(L_SEQ * DI_DIM) / 256, 256, 0, stream>>>(xr_bf, W_conv, b_conv, xcb);
  // convert W_x (reuses w_bf)
  {
    int n4 = (NPROJ * DI_DIM) / 4;
    k_f32_to_bf16<<<(n4 + 255) / 256, 256, 0, stream>>>(W_x, w_bf, n4);
  }
  // GEMM2: proj = xi @ W_x^T + b_x  (2048 x 2080, K=2048), f32 out
  {
    dim3 g((NPROJ + 127) / 128, L_SEQ / 128);
    k_gemm_bt<float><<<g, 256, 0, stream>>>(xcb, w_bf, b_x, proj, L_SEQ, NPROJ, DI_DIM);
  }
  // selective scan (chunked 3-phase)
  {
    dim3 ga(DI_DIM / 256, NCHUNK);
    k_scan_a<<<ga, 256, 0, stream>>>(proj, xcb, A_log, Sdelta, hstate);
    k_scan_b<<<(DI_DIM * NSSM) / 256, 256, 0, stream>>>(A_log, Sdelta, hstate);
    k_scan_c<<<ga, 256, 0, stream>>>(proj, xcb, A_log, hstate, Dv, xr_bf, ybf);
  }
  // convert W_out (reuses w_bf)
  {
    int n4 = (DMODEL * DI_DIM) / 4;
    k_f32_to_bf16<<<(n4 + 255) / 256, 256, 0, stream>>>(W_out, w_bf, n4);
  }
  // GEMM3: out = y @ W_out^T + b_out (2048 x 1024, K=2048), f32 out to d_out
  {
    dim3 g(DMODEL / 128, L_SEQ / 128);
    k_gemm_bt<float><<<g, 256, 0, stream>>>(ybf, w_bf, b_out, out, L_SEQ, DMODEL, DI_DIM);
  }
}